// Round 2
// baseline (26.327 us; speedup 1.0000x reference)
//
#include <hip/hip_runtime.h>
#include <hip/hip_bf16.h>

// RoPE: x (B,S,128) fp32, token_position (B,S) int32 (harness narrows int64).
// out[..., 2j]   = x[2j]*cos(p*f_j) - x[2j+1]*sin(p*f_j)
// out[..., 2j+1] = x[2j]*sin(p*f_j) + x[2j+1]*cos(p*f_j)
// f_j = theta^(-j/64), j = 0..63.
//
// Memory-bound: 64MiB in + 64MiB out ≈ 135MB → ~21us at 6.3 TB/s.
// Each thread: one float4 = 2 RoPE pairs. 32 float4 per 128-elem row.
// sin/cos via raw v_sin_f32/v_cos_f32 (input in REVOLUTIONS, reduced by floor),
// so frequencies are precomputed in revolutions: f_rev = theta^(-j/64)/(2pi).
// Grid stride is a multiple of 32 -> q (and the two freqs) loop-invariant.

#define NEG_LOG2_THETA_OVER_64 (-0.2076205059304644f)  // -log2(10000)/64
#define INV_2PI                (0.15915494309189535f)

__global__ void rope_kernel(const float4* __restrict__ x,
                            const int* __restrict__ pos,
                            float4* __restrict__ out,
                            int total4) {
    const int stride = gridDim.x * blockDim.x;   // multiple of 32
    const int i0 = blockIdx.x * blockDim.x + threadIdx.x;
    const int q = i0 & 31;                       // quad index within row
    const float j0 = (float)(2 * q);
    // frequencies in revolutions (loop-invariant, hoisted)
    const float f0 = exp2f(j0 * NEG_LOG2_THETA_OVER_64) * INV_2PI;
    const float f1 = exp2f((j0 + 1.0f) * NEG_LOG2_THETA_OVER_64) * INV_2PI;

    for (int i = i0; i < total4; i += stride) {
        const int row = i >> 5;                  // 32 float4 per row
        const float p = (float)pos[row];
        const float4 v = x[i];

        float r0 = p * f0;
        float r1 = p * f1;
        r0 -= floorf(r0);                        // range-reduce to [0,1) revs
        r1 -= floorf(r1);
        const float s0 = __builtin_amdgcn_sinf(r0);
        const float c0 = __builtin_amdgcn_cosf(r0);
        const float s1 = __builtin_amdgcn_sinf(r1);
        const float c1 = __builtin_amdgcn_cosf(r1);

        float4 o;
        o.x = v.x * c0 - v.y * s0;
        o.y = v.x * s0 + v.y * c0;
        o.z = v.z * c1 - v.w * s1;
        o.w = v.z * s1 + v.w * c1;
        out[i] = o;
    }
}

extern "C" void kernel_launch(void* const* d_in, const int* in_sizes, int n_in,
                              void* d_out, int out_size, void* d_ws, size_t ws_size,
                              hipStream_t stream) {
    const float4* x   = (const float4*)d_in[0];
    const int*    pos = (const int*)d_in[1];
    float4*       out = (float4*)d_out;

    int total4 = out_size / 4;           // 16*8192*128/4 = 4,194,304 float4s
    int block = 256;
    int grid = (total4 + block - 1) / block;
    if (grid > 2048) grid = 2048;        // grid-stride the rest (8 iters/thread)
    rope_kernel<<<grid, block, 0, stream>>>(x, pos, out, total4);
}

// Round 4
// 26.316 us; speedup vs baseline: 1.0004x; 1.0004x over previous
//
#include <hip/hip_runtime.h>
#include <hip/hip_bf16.h>

// RoPE: x (B,S,128) fp32, token_position (B,S) int32 (harness narrows int64).
// out[..., 2j]   = x[2j]*cos(p*f_j) - x[2j+1]*sin(p*f_j)
// out[..., 2j+1] = x[2j]*sin(p*f_j) + x[2j+1]*cos(p*f_j)
// f_j = theta^(-j/64), j = 0..63.
//
// Memory-bound: 64MiB in + 64MiB out ≈ 135MB → ~21.4us at 6.3 TB/s copy ceiling.
// R2 measured 26.3us (5.1 TB/s). R3: unroll x2 with loads hoisted before
// compute (2 loads in flight/thread) + non-temporal stores (out is write-only;
// don't allocate in L2/L3, keep cache for the input stream).
// NOTE: nontemporal builtins require a NATIVE clang vector type, not HIP's
// float4 class -> use ext_vector_type(4) float.
//
// sin/cos via raw v_sin_f32/v_cos_f32 (input in REVOLUTIONS, fract-reduced);
// freqs precomputed in revolutions: f_rev = theta^(-j/64)/(2pi).
// Grid stride (524288) is a multiple of 32 -> quad index q loop-invariant,
// and divides total4 (4194304) exactly -> no tail in the unrolled loop.

typedef float f32x4 __attribute__((ext_vector_type(4)));

#define NEG_LOG2_THETA_OVER_64 (-0.2076205059304644f)  // -log2(10000)/64
#define INV_2PI                (0.15915494309189535f)

__device__ __forceinline__ f32x4 rope4(f32x4 v, float p, float f0, float f1) {
    float r0 = p * f0;
    float r1 = p * f1;
    r0 -= floorf(r0);                        // revolutions -> [0,1)
    r1 -= floorf(r1);
    const float s0 = __builtin_amdgcn_sinf(r0);
    const float c0 = __builtin_amdgcn_cosf(r0);
    const float s1 = __builtin_amdgcn_sinf(r1);
    const float c1 = __builtin_amdgcn_cosf(r1);
    f32x4 o;
    o.x = v.x * c0 - v.y * s0;
    o.y = v.x * s0 + v.y * c0;
    o.z = v.z * c1 - v.w * s1;
    o.w = v.z * s1 + v.w * c1;
    return o;
}

__global__ void rope_kernel(const f32x4* __restrict__ x,
                            const int* __restrict__ pos,
                            f32x4* __restrict__ out,
                            int total4) {
    const int stride = gridDim.x * blockDim.x;   // multiple of 32
    const int i0 = blockIdx.x * blockDim.x + threadIdx.x;
    const int q = i0 & 31;                       // quad index within row
    const float j0 = (float)(2 * q);
    const float f0 = exp2f(j0 * NEG_LOG2_THETA_OVER_64) * INV_2PI;
    const float f1 = exp2f((j0 + 1.0f) * NEG_LOG2_THETA_OVER_64) * INV_2PI;

    int i = i0;
    // unrolled x2: issue both loads before any compute (2x MLP per thread)
    for (; i + stride < total4; i += 2 * stride) {
        const int ib = i + stride;
        const f32x4 va = x[i];
        const f32x4 vb = x[ib];
        const float pa = (float)pos[i >> 5];
        const float pb = (float)pos[ib >> 5];
        const f32x4 oa = rope4(va, pa, f0, f1);
        const f32x4 ob = rope4(vb, pb, f0, f1);
        __builtin_nontemporal_store(oa, &out[i]);
        __builtin_nontemporal_store(ob, &out[ib]);
    }
    if (i < total4) {
        const f32x4 v = x[i];
        const float p = (float)pos[i >> 5];
        const f32x4 o = rope4(v, p, f0, f1);
        __builtin_nontemporal_store(o, &out[i]);
    }
}

extern "C" void kernel_launch(void* const* d_in, const int* in_sizes, int n_in,
                              void* d_out, int out_size, void* d_ws, size_t ws_size,
                              hipStream_t stream) {
    const f32x4* x   = (const f32x4*)d_in[0];
    const int*   pos = (const int*)d_in[1];
    f32x4*       out = (f32x4*)d_out;

    int total4 = out_size / 4;           // 16*8192*128/4 = 4,194,304 float4s
    int block = 256;
    int grid = (total4 + block - 1) / block;
    if (grid > 2048) grid = 2048;        // grid-stride: 8 float4 per thread
    rope_kernel<<<grid, block, 0, stream>>>(x, pos, out, total4);
}